// Round 1
// baseline (192.771 us; speedup 1.0000x reference)
//
#include <hip/hip_runtime.h>
#include <hip/hip_bf16.h>

// QuantizedConv2d: B=8, Cin=Cout=320, H=W=64, K=3, stride=1, pad=1.
//
// Math: out = scale[co] * (conv_zp_padded_int8(x_int, W) ) + bias_eff[co]
// where bias_eff[co] = bias[co] - scale[co]*zp*sum(W[co]), x padded with zp.
// This is exactly scale*(acc - corr) + bias from the reference (zp integral).

typedef int v4i __attribute__((ext_vector_type(4)));

typedef const unsigned int __attribute__((address_space(1)))* gas_uptr;
typedef unsigned int __attribute__((address_space(3)))* las_uptr;

#define B_   8
#define CIN  320
#define COUT 320
#define H_   64
#define W_   64
#define HP   66
#define WP   66
// padded x: [B][66][66][320] int8 = 11,151,360 B
#define XPAD_BYTES (B_*HP*WP*CIN)
// repacked weights: [co][tap][ci] int8 = 320*9*320 = 921,600 B
#define W8_BYTES (COUT*9*CIN)

// ---------------------------------------------------------------------------
// Kernel 1: per-channel effective bias. Wtot from weight_sum_by_input_channels
// (f32, [O,1,3,3] -> 9 values per co, all integer-valued, exact in f32).
__global__ void bias_eff_kernel(const float* __restrict__ wsum,
                                const float* __restrict__ scale,
                                const float* __restrict__ bias,
                                const float* __restrict__ zp_p,
                                float* __restrict__ be) {
    int co = threadIdx.x;
    if (co < COUT) {
        float s = 0.f;
        #pragma unroll
        for (int tp = 0; tp < 9; ++tp) s += wsum[co*9 + tp];
        be[co] = bias[co] - scale[co] * zp_p[0] * s;
    }
}

// ---------------------------------------------------------------------------
// Kernel 2: weight repack int32 [O][I][3][3] -> int8 [co][tap][ci], rows of
// 2880 bytes per co (K-major for the GEMM B operand). One dword per thread.
__global__ __launch_bounds__(256) void repack_w_kernel(const int* __restrict__ wint,
                                                       unsigned char* __restrict__ w8) {
    int j = blockIdx.x * 256 + threadIdx.x;     // < 230,400 dwords
    int co  = j / 720;
    int r   = j - co * 720;                     // tap*80 + d
    int tap = r / 80;
    int d   = r - tap * 80;
    int ci  = d * 4;
    const int* base = wint + (co * CIN + ci) * 9 + tap;
    unsigned b0 = (unsigned)(base[0]  & 0xFF);
    unsigned b1 = (unsigned)(base[9]  & 0xFF);
    unsigned b2 = (unsigned)(base[18] & 0xFF);
    unsigned b3 = (unsigned)(base[27] & 0xFF);
    ((unsigned*)w8)[j] = b0 | (b1 << 8) | (b2 << 16) | (b3 << 24);
}

// ---------------------------------------------------------------------------
// Kernel 3: quantize + pad. One block per (b, padded row ph). Interior rows:
// coalesced f32 loads (64 consecutive w per wave), quantize, byte-transpose
// through LDS (row stride 324 -> conflict-free), coalesced dword stores of
// NHWC int8. Ring rows/cols filled with zp byte.
__global__ __launch_bounds__(256) void quant_pad_kernel(const float* __restrict__ x,
                                                        unsigned char* __restrict__ xpad,
                                                        const float* __restrict__ inv_p,
                                                        const float* __restrict__ zp_p) {
    __shared__ __align__(16) unsigned char lds[64 * 324];
    int bid = blockIdx.x;
    int b  = bid / HP;
    int ph = bid - b * HP;
    int t  = threadIdx.x;
    float inv = inv_p[0];
    float zp  = zp_p[0];
    int zpi = (int)rintf(zp);
    unsigned zd = ((unsigned)(zpi & 0xFF)) * 0x01010101u;

    unsigned* rowbase = (unsigned*)(xpad + (size_t)((b * HP + ph) * WP) * CIN); // 5280 dwords

    if (ph == 0 || ph == HP - 1) {
        for (int j = t; j < WP * CIN / 4; j += 256) rowbase[j] = zd;
        return;
    }
    int h = ph - 1;
    const float* xrow = x + (size_t)b * CIN * H_ * W_ + h * W_;   // + ci*4096 + w
    int w  = t & 63;
    int cw = t >> 6;            // wave id 0..3
    for (int i = 0; i < 80; ++i) {
        int ci = i * 4 + cw;
        float v = xrow[ci * (H_ * W_) + w];
        float q = rintf(v * inv) + zp;
        q = fminf(fmaxf(q, -128.0f), 127.0f);
        int qi = (int)q;
        lds[w * 324 + ci] = (unsigned char)(qi & 0xFF);
    }
    __syncthreads();
    // edge columns pw=0 and pw=65 (80 dwords each)
    if (t < 80)            rowbase[t] = zd;
    else if (t < 160)      rowbase[65 * 80 + (t - 80)] = zd;
    // interior: 64 pixels * 80 dwords; global dword = 80 + j (pw = p+1)
    const unsigned* ldsd = (const unsigned*)lds;
    for (int j = t; j < 64 * 80; j += 256) {
        int p = j / 80;
        int d = j - p * 80;
        rowbase[80 + j] = ldsd[p * 81 + d];
    }
}

// ---------------------------------------------------------------------------
// Kernel 4: implicit-GEMM conv. C[M=32768][N=320] = A[M][K=2880] x B[K][N].
// Tile 128(M) x 64(N), 4 waves 2x2 each 64x32, mfma_i32_16x16x64_i8,
// K-chunks of 64 bytes (never straddle a tap since 320 = 5*64).
// global_load_lds width=16, lane-order-contiguous LDS (m104 caveat).
__global__ __launch_bounds__(256) void conv_gemm_kernel(const unsigned char* __restrict__ xpad,
                                                        const unsigned char* __restrict__ w8,
                                                        const float* __restrict__ scale,
                                                        const float* __restrict__ be,
                                                        float* __restrict__ out) {
    __shared__ __align__(16) unsigned char Al[128 * 64];
    __shared__ __align__(16) unsigned char Bl[64 * 64];

    int t    = threadIdx.x;
    int lane = t & 63;
    int wave = t >> 6;
    int wm   = wave & 1;      // M half (64 pixels)
    int wn   = wave >> 1;     // N half (32 cout)
    int n0   = blockIdx.x * 64;
    int m0   = blockIdx.y * 128;

    // A staging addresses: 4 lanes per pixel row, 16B each. Tap-(0,0) base;
    // per-chunk offset is wave-uniform.
    int pl0 = t >> 2;                 // pixels 0..63
    int bo  = (t & 3) * 16;
    int pix0 = m0 + pl0;
    int pix1 = pix0 + 64;
    int b0i = pix0 >> 12, hw0 = pix0 & 4095;
    int b1i = pix1 >> 12, hw1 = pix1 & 4095;
    const unsigned char* ap0 = xpad + (size_t)(((b0i * HP + (hw0 >> 6)) * WP + (hw0 & 63)) * CIN) + bo;
    const unsigned char* ap1 = xpad + (size_t)(((b1i * HP + (hw1 >> 6)) * WP + (hw1 & 63)) * CIN) + bo;
    const unsigned char* bp  = w8 + (size_t)(n0 + (t >> 2)) * (9 * CIN) + bo;

    v4i acc[4][2];
    v4i zero = {0, 0, 0, 0};
    #pragma unroll
    for (int i = 0; i < 4; ++i)
        #pragma unroll
        for (int j = 0; j < 2; ++j) acc[i][j] = zero;

    int albase = (wm * 64 + (lane & 15)) * 64 + (lane >> 4) * 16;
    int blbase = (wn * 32 + (lane & 15)) * 64 + (lane >> 4) * 16;

    for (int kh = 0; kh < 3; ++kh) {
        for (int kw = 0; kw < 3; ++kw) {
            int aoff = (kh * WP + kw) * CIN;
            int boff = (kh * 3 + kw) * CIN;
            #pragma unroll 1
            for (int c5 = 0; c5 < 5; ++c5) {
                __builtin_amdgcn_global_load_lds((gas_uptr)(const void*)(ap0 + aoff + c5 * 64),
                                                 (las_uptr)(Al + t * 16), 16, 0, 0);
                __builtin_amdgcn_global_load_lds((gas_uptr)(const void*)(ap1 + aoff + c5 * 64),
                                                 (las_uptr)(Al + 4096 + t * 16), 16, 0, 0);
                __builtin_amdgcn_global_load_lds((gas_uptr)(const void*)(bp + boff + c5 * 64),
                                                 (las_uptr)(Bl + t * 16), 16, 0, 0);
                __syncthreads();   // drains vmcnt -> staged data visible
                v4i a[4], bb[2];
                #pragma unroll
                for (int mi = 0; mi < 4; ++mi)
                    a[mi] = *(const v4i*)(Al + albase + mi * 1024);
                #pragma unroll
                for (int ni = 0; ni < 2; ++ni)
                    bb[ni] = *(const v4i*)(Bl + blbase + ni * 1024);
                #pragma unroll
                for (int mi = 0; mi < 4; ++mi)
                    #pragma unroll
                    for (int ni = 0; ni < 2; ++ni)
                        acc[mi][ni] = __builtin_amdgcn_mfma_i32_16x16x64_i8(a[mi], bb[ni], acc[mi][ni], 0, 0, 0);
                __syncthreads();   // before next chunk overwrites LDS
            }
        }
    }

    // Epilogue: C/D layout col = lane&15, row = (lane>>4)*4 + reg (guide §3).
    // Lane's 4 acc elems are 4 consecutive pixels (w-fastest) -> float4 store.
    int colc = lane & 15;
    int rowq = lane >> 4;
    #pragma unroll
    for (int ni = 0; ni < 2; ++ni) {
        int co = n0 + wn * 32 + ni * 16 + colc;
        float s  = scale[co];
        float bz = be[co];
        #pragma unroll
        for (int mi = 0; mi < 4; ++mi) {
            int pix = m0 + wm * 64 + mi * 16 + rowq * 4;
            int bb2 = pix >> 12;
            int hw  = pix & 4095;
            v4i v = acc[mi][ni];
            float4 o;
            o.x = s * (float)v.x + bz;
            o.y = s * (float)v.y + bz;
            o.z = s * (float)v.z + bz;
            o.w = s * (float)v.w + bz;
            *(float4*)(out + (size_t)(bb2 * COUT + co) * (H_ * W_) + hw) = o;
        }
    }
}

// ---------------------------------------------------------------------------
extern "C" void kernel_launch(void* const* d_in, const int* in_sizes, int n_in,
                              void* d_out, int out_size, void* d_ws, size_t ws_size,
                              hipStream_t stream) {
    const float* x     = (const float*)d_in[0];
    const int*   wint  = (const int*)d_in[1];
    const float* wsum  = (const float*)d_in[2];
    const float* scale = (const float*)d_in[3];
    const float* inv_p = (const float*)d_in[4];
    const float* zp_p  = (const float*)d_in[5];
    const float* bias  = (const float*)d_in[6];
    float* out = (float*)d_out;

    unsigned char* xpad = (unsigned char*)d_ws;
    unsigned char* w8   = xpad + XPAD_BYTES;          // 11,151,360 (16B aligned)
    float*         be   = (float*)(w8 + W8_BYTES);    // + 921,600

    bias_eff_kernel<<<1, 320, 0, stream>>>(wsum, scale, bias, zp_p, be);
    repack_w_kernel<<<(COUT * 720) / 256, 256, 0, stream>>>(wint, w8);
    quant_pad_kernel<<<B_ * HP, 256, 0, stream>>>(x, xpad, inv_p, zp_p);

    dim3 grid(COUT / 64, (B_ * H_ * W_) / 128);       // 5 x 256
    conv_gemm_kernel<<<grid, 256, 0, stream>>>(xpad, w8, scale, be, out);
}

// Round 2
// 163.426 us; speedup vs baseline: 1.1796x; 1.1796x over previous
//
#include <hip/hip_runtime.h>
#include <hip/hip_bf16.h>

// QuantizedConv2d: B=8, Cin=Cout=320, H=W=64, K=3, stride=1, pad=1.
//
// Math: out = scale[co] * conv_zp_padded_int8(x_int, W) + bias_eff[co]
// where bias_eff[co] = bias[co] - scale[co]*zp*sum(W[co]), x padded with zp.
// Exactly scale*(acc - corr) + bias from the reference (zp integral).

typedef int v4i __attribute__((ext_vector_type(4)));

typedef const unsigned int __attribute__((address_space(1)))* gas_uptr;
typedef unsigned int __attribute__((address_space(3)))* las_uptr;

#define B_   8
#define CIN  320
#define COUT 320
#define H_   64
#define W_   64
#define HP   66
#define WP   66
// padded x: [B][66][66][320] int8 = 11,151,360 B
#define XPAD_BYTES (B_*HP*WP*CIN)
// repacked weights: [co][tap][ci] int8 = 320*9*320 = 921,600 B
#define W8_BYTES (COUT*9*CIN)

// ---------------------------------------------------------------------------
// Kernel 1: per-channel effective bias.
__global__ void bias_eff_kernel(const float* __restrict__ wsum,
                                const float* __restrict__ scale,
                                const float* __restrict__ bias,
                                const float* __restrict__ zp_p,
                                float* __restrict__ be) {
    int co = threadIdx.x;
    if (co < COUT) {
        float s = 0.f;
        #pragma unroll
        for (int tp = 0; tp < 9; ++tp) s += wsum[co*9 + tp];
        be[co] = bias[co] - scale[co] * zp_p[0] * s;
    }
}

// ---------------------------------------------------------------------------
// Kernel 2: weight repack int32 [O][I][3][3] -> int8 [co][tap][ci].
__global__ __launch_bounds__(256) void repack_w_kernel(const int* __restrict__ wint,
                                                       unsigned char* __restrict__ w8) {
    int j = blockIdx.x * 256 + threadIdx.x;     // < 230,400 dwords
    int co  = j / 720;
    int r   = j - co * 720;                     // tap*80 + d
    int tap = r / 80;
    int d   = r - tap * 80;
    int ci  = d * 4;
    const int* base = wint + (co * CIN + ci) * 9 + tap;
    unsigned b0 = (unsigned)(base[0]  & 0xFF);
    unsigned b1 = (unsigned)(base[9]  & 0xFF);
    unsigned b2 = (unsigned)(base[18] & 0xFF);
    unsigned b3 = (unsigned)(base[27] & 0xFF);
    ((unsigned*)w8)[j] = b0 | (b1 << 8) | (b2 << 16) | (b3 << 24);
}

// ---------------------------------------------------------------------------
// Kernel 3: quantize + pad, register-transpose version.
// Thread t: wq = t&15 (4 w's), cg = t>>4; 5 iterations each handling a 4x4
// (ci x w) block: 4 float4 loads -> quantize -> pack 4 dwords [w][ci..ci+3]
// -> 4 ds_write_b32 at stride 81 dwords (2-way bank aliasing = free).
__global__ __launch_bounds__(256) void quant_pad_kernel(const float* __restrict__ x,
                                                        unsigned char* __restrict__ xpad,
                                                        const float* __restrict__ inv_p,
                                                        const float* __restrict__ zp_p) {
    __shared__ __align__(16) unsigned lds[64 * 81];    // dwords, row stride 81
    int bid = blockIdx.x;
    int b  = bid / HP;
    int ph = bid - b * HP;
    int t  = threadIdx.x;
    float inv = inv_p[0];
    float zp  = zp_p[0];
    int zpi = (int)rintf(zp);
    unsigned zd = ((unsigned)(zpi & 0xFF)) * 0x01010101u;

    unsigned* rowbase = (unsigned*)(xpad + (size_t)((b * HP + ph) * WP) * CIN); // 5280 dwords

    if (ph == 0 || ph == HP - 1) {
        for (int j = t; j < WP * CIN / 4; j += 256) rowbase[j] = zd;
        return;
    }
    int h = ph - 1;
    const float* xrow = x + (size_t)b * CIN * H_ * W_ + h * W_;   // + ci*4096 + w
    int wq = t & 15;            // w = wq*4 + k
    int cg = t >> 4;            // 0..15
    #pragma unroll
    for (int i = 0; i < 5; ++i) {
        int ci0 = i * 64 + cg * 4;
        float4 f[4];
        #pragma unroll
        for (int j = 0; j < 4; ++j)
            f[j] = *(const float4*)(xrow + (size_t)(ci0 + j) * (H_ * W_) + wq * 4);
        #pragma unroll
        for (int k = 0; k < 4; ++k) {
            unsigned d = 0;
            #pragma unroll
            for (int j = 0; j < 4; ++j) {
                float v = (&f[j].x)[k];
                float q = rintf(v * inv) + zp;
                q = fminf(fmaxf(q, -128.0f), 127.0f);
                int qi = (int)q;
                d |= ((unsigned)(qi & 0xFF)) << (8 * j);
            }
            lds[(wq * 4 + k) * 81 + (ci0 >> 2)] = d;
        }
    }
    __syncthreads();
    // edge columns pw=0 and pw=65 (80 dwords each)
    if (t < 80)            rowbase[t] = zd;
    else if (t < 160)      rowbase[65 * 80 + (t - 80)] = zd;
    // interior: 64 pixels * 80 dwords; global dword = 80 + j (pw = p+1)
    for (int j = t; j < 64 * 80; j += 256) {
        int p = j / 80;
        int d = j - p * 80;
        rowbase[80 + j] = lds[p * 81 + d];
    }
}

// ---------------------------------------------------------------------------
// Kernel 4: implicit-GEMM conv. C[M=32768][N=320] = A[M][K=2880] x B[K][N].
// Tile 128(M) x 64(N), 4 waves 2x2, mfma_i32_16x16x64_i8.
// BK = 320 (one full 3x3 tap): 15 global_load_lds issues -> 1 barrier ->
// 40 MFMAs -> 1 barrier. 9 barrier pairs total (was 45 with BK=64).
// LDS 60 KB -> 2 blocks/CU; staging of one block overlaps compute of other.
__global__ __launch_bounds__(256) void conv_gemm_kernel(const unsigned char* __restrict__ xpad,
                                                        const unsigned char* __restrict__ w8,
                                                        const float* __restrict__ scale,
                                                        const float* __restrict__ be,
                                                        float* __restrict__ out) {
    __shared__ __align__(16) unsigned char Al[5 * 128 * 64];   // [c5][pixel][64]
    __shared__ __align__(16) unsigned char Bl[5 * 64 * 64];    // [c5][co][64]

    int t    = threadIdx.x;
    int lane = t & 63;
    int wave = t >> 6;
    int wm   = wave & 1;      // M half (64 pixels)
    int wn   = wave >> 1;     // N half (32 cout)
    int m0   = blockIdx.x * 128;   // M-tiles in x: blocks sharing an M-tile
    int n0   = blockIdx.y * 64;    // differ by gridDim.x=256 == 0 mod 8 -> same XCD

    // A staging addresses: 4 lanes per pixel, 16B each; tap offset is uniform.
    int pl0 = t >> 2;                 // pixels 0..63
    int bo  = (t & 3) * 16;
    int pix0 = m0 + pl0;
    int pix1 = pix0 + 64;
    int b0i = pix0 >> 12, hw0 = pix0 & 4095;
    int b1i = pix1 >> 12, hw1 = pix1 & 4095;
    const unsigned char* ap0 = xpad + (size_t)(((b0i * HP + (hw0 >> 6)) * WP + (hw0 & 63)) * CIN) + bo;
    const unsigned char* ap1 = xpad + (size_t)(((b1i * HP + (hw1 >> 6)) * WP + (hw1 & 63)) * CIN) + bo;
    const unsigned char* bp  = w8 + (size_t)(n0 + (t >> 2)) * (9 * CIN) + bo;

    v4i acc[4][2];
    v4i zero = {0, 0, 0, 0};
    #pragma unroll
    for (int i = 0; i < 4; ++i)
        #pragma unroll
        for (int j = 0; j < 2; ++j) acc[i][j] = zero;

    int albase = (wm * 64 + (lane & 15)) * 64 + (lane >> 4) * 16;
    int blbase = (wn * 32 + (lane & 15)) * 64 + (lane >> 4) * 16;

    for (int kh = 0; kh < 3; ++kh) {
        #pragma unroll 1
        for (int kw = 0; kw < 3; ++kw) {
            int aoff = (kh * WP + kw) * CIN;
            int boff = (kh * 3 + kw) * CIN;
            // stage one full tap: A 40960 B (10 issues), B 20480 B (5 issues)
            #pragma unroll
            for (int c5 = 0; c5 < 5; ++c5) {
                __builtin_amdgcn_global_load_lds((gas_uptr)(const void*)(ap0 + aoff + c5 * 64),
                                                 (las_uptr)(Al + c5 * 8192 + t * 16), 16, 0, 0);
                __builtin_amdgcn_global_load_lds((gas_uptr)(const void*)(ap1 + aoff + c5 * 64),
                                                 (las_uptr)(Al + c5 * 8192 + 4096 + t * 16), 16, 0, 0);
                __builtin_amdgcn_global_load_lds((gas_uptr)(const void*)(bp + boff + c5 * 64),
                                                 (las_uptr)(Bl + c5 * 4096 + t * 16), 16, 0, 0);
            }
            __syncthreads();   // drains vmcnt -> staged data visible
            #pragma unroll
            for (int c5 = 0; c5 < 5; ++c5) {
                v4i a[4], bb[2];
                #pragma unroll
                for (int mi = 0; mi < 4; ++mi)
                    a[mi] = *(const v4i*)(Al + c5 * 8192 + albase + mi * 1024);
                #pragma unroll
                for (int ni = 0; ni < 2; ++ni)
                    bb[ni] = *(const v4i*)(Bl + c5 * 4096 + blbase + ni * 1024);
                #pragma unroll
                for (int mi = 0; mi < 4; ++mi)
                    #pragma unroll
                    for (int ni = 0; ni < 2; ++ni)
                        acc[mi][ni] = __builtin_amdgcn_mfma_i32_16x16x64_i8(a[mi], bb[ni], acc[mi][ni], 0, 0, 0);
            }
            __syncthreads();   // before next tap overwrites LDS
        }
    }

    // Epilogue: C/D layout col = lane&15, row = (lane>>4)*4 + reg.
    // Lane's 4 acc elems are 4 consecutive pixels (w-fastest) -> float4 store.
    int colc = lane & 15;
    int rowq = lane >> 4;
    #pragma unroll
    for (int ni = 0; ni < 2; ++ni) {
        int co = n0 + wn * 32 + ni * 16 + colc;
        float s  = scale[co];
        float bz = be[co];
        #pragma unroll
        for (int mi = 0; mi < 4; ++mi) {
            int pix = m0 + wm * 64 + mi * 16 + rowq * 4;
            int bb2 = pix >> 12;
            int hw  = pix & 4095;
            v4i v = acc[mi][ni];
            float4 o;
            o.x = s * (float)v.x + bz;
            o.y = s * (float)v.y + bz;
            o.z = s * (float)v.z + bz;
            o.w = s * (float)v.w + bz;
            *(float4*)(out + (size_t)(bb2 * COUT + co) * (H_ * W_) + hw) = o;
        }
    }
}

// ---------------------------------------------------------------------------
extern "C" void kernel_launch(void* const* d_in, const int* in_sizes, int n_in,
                              void* d_out, int out_size, void* d_ws, size_t ws_size,
                              hipStream_t stream) {
    const float* x     = (const float*)d_in[0];
    const int*   wint  = (const int*)d_in[1];
    const float* wsum  = (const float*)d_in[2];
    const float* scale = (const float*)d_in[3];
    const float* inv_p = (const float*)d_in[4];
    const float* zp_p  = (const float*)d_in[5];
    const float* bias  = (const float*)d_in[6];
    float* out = (float*)d_out;

    unsigned char* xpad = (unsigned char*)d_ws;
    unsigned char* w8   = xpad + XPAD_BYTES;          // 11,151,360 (16B aligned)
    float*         be   = (float*)(w8 + W8_BYTES);    // + 921,600

    bias_eff_kernel<<<1, 320, 0, stream>>>(wsum, scale, bias, zp_p, be);
    repack_w_kernel<<<(COUT * 720) / 256, 256, 0, stream>>>(wint, w8);
    quant_pad_kernel<<<B_ * HP, 256, 0, stream>>>(x, xpad, inv_p, zp_p);

    dim3 grid((B_ * H_ * W_) / 128, COUT / 64);       // 256 x 5, M fastest
    conv_gemm_kernel<<<grid, 256, 0, stream>>>(xpad, w8, scale, be, out);
}

// Round 3
// 161.299 us; speedup vs baseline: 1.1951x; 1.0132x over previous
//
#include <hip/hip_runtime.h>
#include <hip/hip_bf16.h>

// QuantizedConv2d: B=8, Cin=Cout=320, H=W=64, K=3, stride=1, pad=1.
// out = scale[co] * conv_zp_padded_int8(x_int, W) + bias_eff[co]
// bias_eff[co] = bias[co] - scale[co]*zp*sum(W[co]); x padded with zp byte.

typedef int v4i __attribute__((ext_vector_type(4)));

typedef const unsigned int __attribute__((address_space(1)))* gas_uptr;
typedef unsigned int __attribute__((address_space(3)))* las_uptr;

#define B_   8
#define CIN  320
#define COUT 320
#define H_   64
#define W_   64
#define HW_  4096
#define HP   66
#define WP   66
#define XPAD_BYTES (B_*HP*WP*CIN)
#define W8_BYTES (COUT*9*CIN)

// ---------------------------------------------------------------------------
// Kernel 1: weight repack int32 [O][I][3][3] -> int8 [co][tap][ci], fused
// with per-channel effective bias (first 320 global threads).
__global__ __launch_bounds__(256) void repack_bias_kernel(const int* __restrict__ wint,
                                                          unsigned char* __restrict__ w8,
                                                          const float* __restrict__ wsum,
                                                          const float* __restrict__ scale,
                                                          const float* __restrict__ bias,
                                                          const float* __restrict__ zp_p,
                                                          float* __restrict__ be) {
    int j = blockIdx.x * 256 + threadIdx.x;     // < 230,400 dwords
    if (j < COUT) {
        float s = 0.f;
        #pragma unroll
        for (int tp = 0; tp < 9; ++tp) s += wsum[j*9 + tp];
        be[j] = bias[j] - scale[j] * zp_p[0] * s;
    }
    int co  = j / 720;
    int r   = j - co * 720;                     // tap*80 + d
    int tap = r / 80;
    int d   = r - tap * 80;
    int ci  = d * 4;
    const int* base = wint + (co * CIN + ci) * 9 + tap;
    unsigned b0 = (unsigned)(base[0]  & 0xFF);
    unsigned b1 = (unsigned)(base[9]  & 0xFF);
    unsigned b2 = (unsigned)(base[18] & 0xFF);
    unsigned b3 = (unsigned)(base[27] & 0xFF);
    ((unsigned*)w8)[j] = b0 | (b1 << 8) | (b2 << 16) | (b3 << 24);
}

// ---------------------------------------------------------------------------
// Kernel 2: quantize + pad (register transpose; LDS dword writes stride 81).
__global__ __launch_bounds__(256) void quant_pad_kernel(const float* __restrict__ x,
                                                        unsigned char* __restrict__ xpad,
                                                        const float* __restrict__ inv_p,
                                                        const float* __restrict__ zp_p) {
    __shared__ __align__(16) unsigned lds[64 * 81];
    int bid = blockIdx.x;
    int b  = bid / HP;
    int ph = bid - b * HP;
    int t  = threadIdx.x;
    float inv = inv_p[0];
    float zp  = zp_p[0];
    int zpi = (int)rintf(zp);
    unsigned zd = ((unsigned)(zpi & 0xFF)) * 0x01010101u;

    unsigned* rowbase = (unsigned*)(xpad + (size_t)((b * HP + ph) * WP) * CIN);

    if (ph == 0 || ph == HP - 1) {
        for (int j = t; j < WP * CIN / 4; j += 256) rowbase[j] = zd;
        return;
    }
    int h = ph - 1;
    const float* xrow = x + (size_t)b * CIN * H_ * W_ + h * W_;
    int wq = t & 15;
    int cg = t >> 4;
    #pragma unroll
    for (int i = 0; i < 5; ++i) {
        int ci0 = i * 64 + cg * 4;
        float4 f[4];
        #pragma unroll
        for (int jj = 0; jj < 4; ++jj)
            f[jj] = *(const float4*)(xrow + (size_t)(ci0 + jj) * HW_ + wq * 4);
        #pragma unroll
        for (int k = 0; k < 4; ++k) {
            unsigned d = 0;
            #pragma unroll
            for (int jj = 0; jj < 4; ++jj) {
                float v = (&f[jj].x)[k];
                float q = rintf(v * inv) + zp;
                q = fminf(fmaxf(q, -128.0f), 127.0f);
                int qi = (int)q;
                d |= ((unsigned)(qi & 0xFF)) << (8 * jj);
            }
            lds[(wq * 4 + k) * 81 + (ci0 >> 2)] = d;
        }
    }
    __syncthreads();
    if (t < 80)            rowbase[t] = zd;
    else if (t < 160)      rowbase[65 * 80 + (t - 80)] = zd;
    for (int j = t; j < 64 * 80; j += 256) {
        int p = j / 80;
        int d = j - p * 80;
        rowbase[80 + j] = lds[p * 81 + d];
    }
}

// ---------------------------------------------------------------------------
// Kernel 3: implicit-GEMM conv. C[32768][320] = A[32768][2880] x B[2880][320].
// Tile 128(M) x 160(N), 4 waves 2(M)x2(N), wave = 64x80 = 4x5 of 16x16x64 i8.
// A: staged to LDS per tap (global_load_lds w16, XOR-swizzled source so b128
//    fragment reads are 2-way bank-aliased = free).
// B: NEVER in LDS — direct global_load_dwordx4 into registers (w8 layout is
//    already the MFMA B-fragment layout); all 25 tap loads issued before the
//    staging barrier, consumed latency-free in the MFMA phase.
__global__ __launch_bounds__(256, 2) void conv_gemm_kernel(const unsigned char* __restrict__ xpad,
                                                           const unsigned char* __restrict__ w8,
                                                           const float* __restrict__ scale,
                                                           const float* __restrict__ be,
                                                           float* __restrict__ out) {
    __shared__ __align__(16) unsigned char Al[5 * 128 * 64];   // 40,960 B

    int t    = threadIdx.x;
    int lane = t & 63;
    int wave = t >> 6;
    int wm   = wave & 1;           // M half (64 pixels)
    int wn   = wave >> 1;          // N half (80 couts)
    int m0   = blockIdx.x * 128;   // M fastest; N-pair blocks differ by 256 = same XCD
    int n0   = blockIdx.y * 160;

    // --- A staging source addresses (16 B per lane, swizzled sub-chunk) ---
    int p  = t >> 2;                          // LDS row 0..63 (and +64)
    int qs = (t & 3) ^ ((p >> 1) & 3);        // source sub-chunk for slot t&3
    int pix0 = m0 + p;
    int pix1 = pix0 + 64;
    int b0i = pix0 >> 12, hw0 = pix0 & 4095;
    int b1i = pix1 >> 12, hw1 = pix1 & 4095;
    const unsigned char* ap0 = xpad + (size_t)(((b0i * HP + (hw0 >> 6)) * WP + (hw0 & 63)) * CIN) + qs * 16;
    const unsigned char* ap1 = xpad + (size_t)(((b1i * HP + (hw1 >> 6)) * WP + (hw1 & 63)) * CIN) + qs * 16;

    // --- A fragment LDS addresses (swizzle-corrected) ---
    int colc = lane & 15;
    int q    = lane >> 4;
    int aAddr[4];
    #pragma unroll
    for (int mi = 0; mi < 4; ++mi) {
        int P = wm * 64 + mi * 16 + colc;          // LDS row 0..127
        aAddr[mi] = P * 64 + ((q ^ ((P >> 1) & 3)) * 16);
    }

    // --- B fragment base pointers (row = co, direct from global) ---
    const unsigned char* bptr[5];
    #pragma unroll
    for (int ni = 0; ni < 5; ++ni) {
        int co = n0 + wn * 80 + ni * 16 + colc;
        bptr[ni] = w8 + (size_t)co * (9 * CIN) + q * 16;
    }

    v4i acc[4][5];
    v4i zero = {0, 0, 0, 0};
    #pragma unroll
    for (int mi = 0; mi < 4; ++mi)
        #pragma unroll
        for (int ni = 0; ni < 5; ++ni) acc[mi][ni] = zero;

    #pragma unroll 1
    for (int kh = 0; kh < 3; ++kh) {
        #pragma unroll 1
        for (int kw = 0; kw < 3; ++kw) {
            int aoff = (kh * WP + kw) * CIN;
            int boff = (kh * 3 + kw) * CIN;

            // issue all 25 B loads for this tap (immediate offsets, L2 hits)
            v4i bf[5][5];
            #pragma unroll
            for (int c5 = 0; c5 < 5; ++c5)
                #pragma unroll
                for (int ni = 0; ni < 5; ++ni)
                    bf[c5][ni] = *(const v4i*)(bptr[ni] + boff + c5 * 64);

            // stage A tap into LDS (10 x 16B-wide DMA)
            #pragma unroll
            for (int c5 = 0; c5 < 5; ++c5) {
                __builtin_amdgcn_global_load_lds((gas_uptr)(const void*)(ap0 + aoff + c5 * 64),
                                                 (las_uptr)(Al + c5 * 8192 + t * 16), 16, 0, 0);
                __builtin_amdgcn_global_load_lds((gas_uptr)(const void*)(ap1 + aoff + c5 * 64),
                                                 (las_uptr)(Al + c5 * 8192 + 4096 + t * 16), 16, 0, 0);
            }
            __syncthreads();   // drains vmcnt: A staged, B in regs

            #pragma unroll
            for (int c5 = 0; c5 < 5; ++c5) {
                v4i a[4];
                #pragma unroll
                for (int mi = 0; mi < 4; ++mi)
                    a[mi] = *(const v4i*)(Al + c5 * 8192 + aAddr[mi]);
                #pragma unroll
                for (int mi = 0; mi < 4; ++mi)
                    #pragma unroll
                    for (int ni = 0; ni < 5; ++ni)
                        acc[mi][ni] = __builtin_amdgcn_mfma_i32_16x16x64_i8(a[mi], bf[c5][ni], acc[mi][ni], 0, 0, 0);
            }
            __syncthreads();   // before next tap overwrites LDS
        }
    }

    // Epilogue: C/D layout col = lane&15 (co), row = q*4 + reg (pixel).
    #pragma unroll
    for (int ni = 0; ni < 5; ++ni) {
        int co = n0 + wn * 80 + ni * 16 + colc;
        float s  = scale[co];
        float bz = be[co];
        #pragma unroll
        for (int mi = 0; mi < 4; ++mi) {
            int pix = m0 + wm * 64 + mi * 16 + q * 4;
            int bb2 = pix >> 12;
            int hw  = pix & 4095;
            v4i v = acc[mi][ni];
            float4 o;
            o.x = s * (float)v.x + bz;
            o.y = s * (float)v.y + bz;
            o.z = s * (float)v.z + bz;
            o.w = s * (float)v.w + bz;
            *(float4*)(out + (size_t)(bb2 * COUT + co) * HW_ + hw) = o;
        }
    }
}

// ---------------------------------------------------------------------------
extern "C" void kernel_launch(void* const* d_in, const int* in_sizes, int n_in,
                              void* d_out, int out_size, void* d_ws, size_t ws_size,
                              hipStream_t stream) {
    const float* x     = (const float*)d_in[0];
    const int*   wint  = (const int*)d_in[1];
    const float* wsum  = (const float*)d_in[2];
    const float* scale = (const float*)d_in[3];
    const float* inv_p = (const float*)d_in[4];
    const float* zp_p  = (const float*)d_in[5];
    const float* bias  = (const float*)d_in[6];
    float* out = (float*)d_out;

    unsigned char* xpad = (unsigned char*)d_ws;
    unsigned char* w8   = xpad + XPAD_BYTES;
    float*         be   = (float*)(w8 + W8_BYTES);

    repack_bias_kernel<<<(COUT * 720) / 256, 256, 0, stream>>>(wint, w8, wsum, scale, bias, zp_p, be);
    quant_pad_kernel<<<B_ * HP, 256, 0, stream>>>(x, xpad, inv_p, zp_p);

    dim3 grid((B_ * H_ * W_) / 128, COUT / 160);      // 256 x 2, M fastest
    conv_gemm_kernel<<<grid, 256, 0, stream>>>(xpad, w8, scale, be, out);
}